// Round 11
// baseline (62576.239 us; speedup 1.0000x reference)
//
#include <hip/hip_runtime.h>
#include <stdint.h>
#include <math.h>

// Persistent barrier-free 2-layer LSTM rollout, MI355X (gfx950).
// v12 = TRUE ONE-HOP structure. Ledger r0-r11: Lambda (~1.75us) is
// intrinsic store->visibility latency (insensitive to every consumer- and
// producer-side knob tested); v4/v7's one-round failed because the cand
// SELECT was a second DEPENDENT poll (~Lambda each, regardless of
// freshness). v12 removes it: h1[j], candA[j], candB[j] (3 x f16) + 16-bit
// tag pack into ONE u64 slot. Per step: ONE poll (16 slots/lane, same
// total as v1/v6's two polls), then all-local: z=W2.h1 -> s -> cand by
// bit-shift -> 24 rows -> publish {h1(t+1), candA', candB'}.
// Traffic/step identical to v1/v6 (16 slot-loads, 2 publishes) -> respects
// the established fabric law. Cycle = Lambda + C (~0.9us) vs v6's
// 2*Lambda + 0.45.
// Interlock: parity double-buffer; slots of tag T (parity T&1) overwritten
// only at publish of T+2, which requires a full poll of T+1, which
// requires all WGs published T+1, which requires all consumed T. SAFE.
// Numerics bit-identical to v1/v4: same f16 rounding, same per-row reduce
// order, same gate math (cand branches s'=0/1 exact), same RNG.

#define H     1024
#define NSTEP 8192
#define NWG   512
#define BLK   64
#define NROW  25   // 0-7 Wih1 (4 gates x 2 units), 8-15 Whh0, 16-23 Whh1, 24 W2

typedef _Float16 h2 __attribute__((ext_vector_type(2)));
typedef _Float16 h8 __attribute__((ext_vector_type(8)));

union U32H2 { uint32_t u; h2 v; };

__device__ __forceinline__ uint16_t f16b(float x){
  union { _Float16 h; uint16_t u; } c; c.h = (_Float16)x; return c.u;
}

// record slot: {f16 h1 [0:16), f16 candA [16:32), f16 candB [32:48), tag [48:64)}
__device__ __forceinline__ unsigned long long pack_rec(float h1v, float hA, float hB, uint32_t tag){
  return  (unsigned long long)f16b(h1v)
       | ((unsigned long long)f16b(hA)  << 16)
       | ((unsigned long long)f16b(hB)  << 32)
       | ((unsigned long long)(tag & 0xFFFFu) << 48);
}

// bootstrap slot: {h2 pair [0:32), tag [48:64)}
__device__ __forceinline__ unsigned long long pack_boot(float v0, float v1, uint32_t tag){
  U32H2 p; p.v.x = (_Float16)v0; p.v.y = (_Float16)v1;
  return (unsigned long long)p.u | ((unsigned long long)(tag & 0xFFFFu) << 48);
}

__device__ __forceinline__ uint32_t rtag(unsigned long long v){ return (uint32_t)(v >> 48); }

// Exact JAX threefry2x32.
__device__ __forceinline__ uint2 tf2x32(uint32_t k0, uint32_t k1, uint32_t x0, uint32_t x1){
  uint32_t k2 = k0 ^ k1 ^ 0x1BD11BDAu;
  x0 += k0; x1 += k1;
#define TFR(r) { x0 += x1; x1 = (x1 << (r)) | (x1 >> (32 - (r))); x1 ^= x0; }
  TFR(13) TFR(15) TFR(26) TFR(6)
  x0 += k1; x1 += k2 + 1u;
  TFR(17) TFR(29) TFR(16) TFR(24)
  x0 += k2; x1 += k0 + 2u;
  TFR(13) TFR(15) TFR(26) TFR(6)
  x0 += k0; x1 += k1 + 3u;
  TFR(17) TFR(29) TFR(16) TFR(24)
  x0 += k1; x1 += k2 + 4u;
  TFR(13) TFR(15) TFR(26) TFR(6)
  x0 += k2; x1 += k0 + 5u;
#undef TFR
  uint2 r; r.x = x0; r.y = x1; return r;
}

// keys = threefry_split(key(42), 8192)
__device__ __forceinline__ uint32_t jax_word(uint32_t i){
  return (i < 8192u) ? tf2x32(0u, 42u, i, i + 8192u).x
                     : tf2x32(0u, 42u, i - 8192u, i).y;
}

__device__ __forceinline__ float wred64(float x){
  #pragma unroll
  for(int off = 32; off > 0; off >>= 1) x += __shfl_xor(x, off, 64);
  return x;
}

#if __has_builtin(__builtin_amdgcn_fdot2)
__device__ __forceinline__ float fdot2f(h2 a, h2 b, float c){ return __builtin_amdgcn_fdot2(a, b, c, false); }
#else
__device__ __forceinline__ float fdot2f(h2 a, h2 b, float c){
  return (float)a.x * (float)b.x + (float)a.y * (float)b.y + c;
}
#endif

__device__ __forceinline__ float sigm(float x){
  x = fminf(fmaxf(x, -30.f), 30.f);
  return 1.f / (1.f + __expf(-x));
}
__device__ __forceinline__ float tanh_f(float x){
  x = fminf(fmaxf(x, -15.f), 15.f);
  float e = __expf(2.f * x);
  return (e - 1.f) / (e + 1.f);
}

__device__ __forceinline__ unsigned long long ld_slot(const unsigned long long* p){
  return __hip_atomic_load((unsigned long long*)p, __ATOMIC_RELAXED, __HIP_MEMORY_SCOPE_AGENT);
}
__device__ __forceinline__ void st_slot(unsigned long long* p, unsigned long long v){
  __hip_atomic_store(p, v, __ATOMIC_RELAXED, __HIP_MEMORY_SCOPE_AGENT);
}

// 2-deep pipelined spin on one slot (v10-proven).
__device__ __forceinline__ unsigned long long spin2(const unsigned long long* p,
                                                    uint32_t tag,
                                                    unsigned long long init){
  if(rtag(init) == tag) return init;
  unsigned long long a = ld_slot(p);
  unsigned long long b = ld_slot(p);
  while(true){
    if(rtag(a) == tag) return a;
    a = ld_slot(p);
    if(rtag(b) == tag) return b;
    b = ld_slot(p);
  }
}

// ONE poll per step: 16 contiguous slots/lane (records of WGs 4l..4l+4 and
// 256+4l..256+4l+4; 2 slots per WG). v6/v10 wait shape: batched snapshot,
// pipelined sentinel on slot 0, one batched refresh, lazy straggler walk.
__device__ __forceinline__ void poll16(const unsigned long long* __restrict__ buf,
                                       uint32_t tag, int lane, unsigned long long* pv){
  const unsigned long long* p0 = buf + (lane << 3);
  const unsigned long long* p1 = buf + 512 + (lane << 3);
  #pragma unroll
  for(int k = 0; k < 8; k++){ pv[k] = ld_slot(p0 + k); pv[8 + k] = ld_slot(p1 + k); }

  pv[0] = spin2(p0, tag, pv[0]);

  bool any = false;
  #pragma unroll
  for(int k = 1; k < 16; k++) any |= (rtag(pv[k]) != tag);
  if(any){
    #pragma unroll
    for(int k = 1; k < 16; k++){
      if(rtag(pv[k]) != tag){
        const unsigned long long* p = (k < 8) ? (p0 + k) : (p1 + (k - 8));
        pv[k] = ld_slot(p);
      }
    }
    #pragma unroll
    for(int k = 1; k < 16; k++){
      const unsigned long long* p = (k < 8) ? (p0 + k) : (p1 + (k - 8));
      pv[k] = spin2(p, tag, pv[k]);
    }
  }
}

// Bootstrap poll (8 slots, old h2-pair format, tag at [48:64)).
__device__ __forceinline__ void poll_boot(const unsigned long long* __restrict__ buf,
                                          uint32_t tag, int lane, h2* hv){
  const unsigned long long* p0 = buf + (lane << 2);
  const unsigned long long* p1 = buf + 256 + (lane << 2);
  unsigned long long pv[8];
  #pragma unroll
  for(int k = 0; k < 4; k++){ pv[k] = ld_slot(p0 + k); pv[4 + k] = ld_slot(p1 + k); }
  pv[0] = spin2(p0, tag, pv[0]);
  bool any = false;
  #pragma unroll
  for(int k = 1; k < 8; k++) any |= (rtag(pv[k]) != tag);
  if(any){
    #pragma unroll
    for(int k = 1; k < 8; k++){
      if(rtag(pv[k]) != tag){
        const unsigned long long* p = (k < 4) ? (p0 + k) : (p1 + (k - 4));
        pv[k] = ld_slot(p);
      }
    }
    #pragma unroll
    for(int k = 1; k < 8; k++){
      const unsigned long long* p = (k < 4) ? (p0 + k) : (p1 + (k - 4));
      pv[k] = spin2(p, tag, pv[k]);
    }
  }
  #pragma unroll
  for(int k = 0; k < 8; k++){ U32H2 u; u.u = (uint32_t)pv[k]; hv[k] = u.v; }
}

// Row dot partial: lane l covers h2 [4l,4l+4) and [256+4l,+4): two b128
// LDS reads, lane stride 16B -> conflict-free.
__device__ __forceinline__ float row_part(const h2* __restrict__ wrow, int lane, const h2* hv){
  h8 wl = *(const h8*)(wrow + (lane << 2));
  h8 wh = *(const h8*)(wrow + 256 + (lane << 2));
  float a0 = 0.f, a1 = 0.f;
  h2 w;
  w = __builtin_shufflevector(wl, wl, 0, 1); a0 = fdot2f(w, hv[0], a0);
  w = __builtin_shufflevector(wl, wl, 2, 3); a1 = fdot2f(w, hv[1], a1);
  w = __builtin_shufflevector(wl, wl, 4, 5); a0 = fdot2f(w, hv[2], a0);
  w = __builtin_shufflevector(wl, wl, 6, 7); a1 = fdot2f(w, hv[3], a1);
  w = __builtin_shufflevector(wh, wh, 0, 1); a0 = fdot2f(w, hv[4], a0);
  w = __builtin_shufflevector(wh, wh, 2, 3); a1 = fdot2f(w, hv[5], a1);
  w = __builtin_shufflevector(wh, wh, 4, 5); a0 = fdot2f(w, hv[6], a0);
  w = __builtin_shufflevector(wh, wh, 6, 7); a1 = fdot2f(w, hv[7], a1);
  return a0 + a1;
}

__global__ void __launch_bounds__(BLK)
lstm_persist(const float* __restrict__ ctx,  const float* __restrict__ W1p,  const float* __restrict__ b1p,
             const float* __restrict__ Wih0, const float* __restrict__ Whh0,
             const float* __restrict__ bih0, const float* __restrict__ bhh0,
             const float* __restrict__ Wih1, const float* __restrict__ Whh1,
             const float* __restrict__ bih1, const float* __restrict__ bhh1,
             const float* __restrict__ W2p,  const float* __restrict__ b2p,
             float* __restrict__ out,
             unsigned long long* __restrict__ h0boot,   // 512 (bootstrap only)
             unsigned long long* __restrict__ ab)       // [2][1024] parity records
{
  __shared__ h2 w[NROW][H/2];   // 51.2 KB

  const int lane = threadIdx.x;   // single wave per WG
  const int wg   = blockIdx.x;
  const int j0   = wg << 1;       // this wave's two h-units: j0, j0+1

  // ---- one-time: stage 25 rows as f16 (coalesced float4 reads)
  #pragma unroll 1
  for(int r = 0; r < NROW; r++){
    const float* rowp;
    if(r < 8)      { int g = r & 3,        j = j0 + (r >> 2);        rowp = Wih1 + (size_t)(g*H + j)*H; }
    else if(r < 16){ int rr = r - 8;  int g = rr & 3, j = j0 + (rr >> 2); rowp = Whh0 + (size_t)(g*H + j)*H; }
    else if(r < 24){ int rr = r - 16; int g = rr & 3, j = j0 + (rr >> 2); rowp = Whh1 + (size_t)(g*H + j)*H; }
    else           rowp = W2p;
    const float4* s4 = (const float4*)rowp;
    #pragma unroll
    for(int it = 0; it < 4; it++){
      float4 f = s4[lane + (it << 6)];
      h2 pa; pa.x = (_Float16)f.x; pa.y = (_Float16)f.y;
      h2 pb; pb.x = (_Float16)f.z; pb.y = (_Float16)f.w;
      const int ci = (lane + (it << 6)) << 1;
      w[r][ci] = pa; w[r][ci + 1] = pb;
    }
  }
  __syncthreads();

  // per-wave scalars for both units (uniform across lanes)
  float b0g[8], b1g[8], w0g[8];
  #pragma unroll
  for(int e = 0; e < 2; e++){
    const int j = j0 + e;
    #pragma unroll
    for(int g = 0; g < 4; g++){
      b0g[4*e + g] = bih0[g*H + j] + bhh0[g*H + j];
      b1g[4*e + g] = bih1[g*H + j] + bhh1[g*H + j];
      w0g[4*e + g] = Wih0[g*H + j];
    }
  }
  const float b2v = b2p[0];

  // x0 = W1 @ context + b1
  float xacc = 0.f;
  for(int c = lane; c < 512; c += 64) xacc += W1p[c] * ctx[c];
  const float x0 = wred64(xacc) + b1p[0];

  float c0[2], c1[2] = {0.f, 0.f}, logp = 0.f;
  float c0A[2], c0B[2];

  // h0(0) from x0; publish bootstrap (tag 1)
  {
    float h0v[2];
    #pragma unroll
    for(int e = 0; e < 2; e++){
      float gi = sigm (w0g[4*e+0]*x0 + b0g[4*e+0]);
      float gg = tanh_f(w0g[4*e+2]*x0 + b0g[4*e+2]);
      float go = sigm (w0g[4*e+3]*x0 + b0g[4*e+3]);
      c0[e] = gi * gg;
      h0v[e] = go * tanh_f(c0[e]);
    }
    if(lane == 0)
      st_slot(&h0boot[wg], pack_boot(h0v[0], h0v[1], 1u));
  }

  h2 hv0[8], hv1[8];
  poll_boot(h0boot, 1u, lane, hv0);   // full h0(0)

  // ---- pre-loop: 16 rows from h0(0) -> h1(0) + candidates h0(1)|s'=0,1;
  //      publish record tag 1 -> parity 1 ----
  {
    float rr[16];
    #pragma unroll
    for(int r = 0; r < 8; r++) rr[r]     = row_part(&w[r][0],     lane, hv0);  // Wih1
    #pragma unroll
    for(int r = 0; r < 8; r++) rr[8 + r] = row_part(&w[8 + r][0], lane, hv0);  // Whh0
    #pragma unroll
    for(int off = 32; off > 0; off >>= 1){
      #pragma unroll
      for(int r = 0; r < 16; r++) rr[r] += __shfl_xor(rr[r], off, 64);
    }
    float h1v[2], hA[2], hB[2];
    #pragma unroll
    for(int e = 0; e < 2; e++){
      // h1(0): a1(-1)=0
      float gi = sigm (rr[4*e+0] + b1g[4*e+0]);
      float gf = sigm (rr[4*e+1] + b1g[4*e+1]);
      float gg = tanh_f(rr[4*e+2] + b1g[4*e+2]);
      float go = sigm (rr[4*e+3] + b1g[4*e+3]);
      c1[e] = gf*c1[e] + gi*gg;
      h1v[e] = go * tanh_f(c1[e]);
      // candidates from a0 = Whh0@h0(0)
      float a0c = rr[8+4*e+0], a1c = rr[8+4*e+1], a2c = rr[8+4*e+2], a3c = rr[8+4*e+3];
      float giA = sigm (a0c + b0g[4*e+0]);
      float gfA = sigm (a1c + b0g[4*e+1]);
      float ggA = tanh_f(a2c + b0g[4*e+2]);
      float goA = sigm (a3c + b0g[4*e+3]);
      c0A[e] = gfA*c0[e] + giA*ggA; hA[e] = goA * tanh_f(c0A[e]);
      float giB = sigm (a0c + w0g[4*e+0] + b0g[4*e+0]);
      float gfB = sigm (a1c + w0g[4*e+1] + b0g[4*e+1]);
      float ggB = tanh_f(a2c + w0g[4*e+2] + b0g[4*e+2]);
      float goB = sigm (a3c + w0g[4*e+3] + b0g[4*e+3]);
      c0B[e] = gfB*c0[e] + giB*ggB; hB[e] = goB * tanh_f(c0B[e]);
    }
    if(lane == 0){
      unsigned long long* wb = ab + 1024;   // parity 1
      st_slot(wb + 2*wg,     pack_rec(h1v[0], hA[0], hB[0], 1u));
      st_slot(wb + 2*wg + 1, pack_rec(h1v[1], hA[1], hB[1], 1u));
    }
  }

  // u(0)
  float u;
  {
    const uint32_t kk0 = jax_word(0u), kk1 = jax_word(1u);
    const uint32_t bits = tf2x32(kk0, kk1, 0u, 0u).x;
    u = __uint_as_float((bits >> 9) | 0x3f800000u) - 1.0f;
  }

  #pragma unroll 1
  for(int t = 0; t < NSTEP; t++){
    const uint32_t tau = (uint32_t)t + 1u;   // record tag consumed this step

    // ---- ONE poll: records {h1(t), candA, candB} ----
    const unsigned long long* bp = ab + ((size_t)(tau & 1u) << 10);
    unsigned long long pv[16];
    poll16(bp, tau, lane, pv);

    // unpack h1(t) fragments: slot 2k = unit 8l+2k (even), 2k+1 = odd
    #pragma unroll
    for(int k = 0; k < 8; k++){
      U32H2 uu;
      uu.u = ((uint32_t)pv[2*k] & 0xFFFFu) | (((uint32_t)pv[2*k+1] & 0xFFFFu) << 16);
      hv1[k] = uu.v;
    }

    // resolve: z = W2 @ h1(t) -> p -> s(t)
    float z = row_part(&w[24][0], lane, hv1);
    z = wred64(z) + b2v;
    const float p = sigm(z);
    const float sv = (u < p) ? 1.f : 0.f;
    const bool sb = (sv != 0.f);

    // select candidate h0(t+1): pure bit-shift, NO second poll
    const uint32_t sh = sb ? 32u : 16u;
    #pragma unroll
    for(int k = 0; k < 8; k++){
      U32H2 uu;
      uu.u = ((uint32_t)(pv[2*k] >> sh) & 0xFFFFu)
           | (((uint32_t)(pv[2*k+1] >> sh) & 0xFFFFu) << 16);
      hv0[k] = uu.v;
    }
    #pragma unroll
    for(int e = 0; e < 2; e++) c0[e] = sb ? c0B[e] : c0A[e];

    // ---- 24 rows: Wih1@h0sel, Whh0@h0sel, Whh1@h1 ----
    float rr[24];
    #pragma unroll
    for(int r = 0; r < 8; r++) rr[r]      = row_part(&w[r][0],      lane, hv0);  // Wih1
    #pragma unroll
    for(int r = 0; r < 8; r++) rr[8 + r]  = row_part(&w[8 + r][0],  lane, hv0);  // Whh0
    #pragma unroll
    for(int r = 0; r < 8; r++) rr[16 + r] = row_part(&w[16 + r][0], lane, hv1);  // Whh1
    #pragma unroll
    for(int off = 32; off > 0; off >>= 1){
      #pragma unroll
      for(int r = 0; r < 24; r++) rr[r] += __shfl_xor(rr[r], off, 64);
    }

    // cells: h1(t+1) + candidates h0(t+2)|s'=0,1 -> publish (tag tau+1)
    {
      float h1v[2], hA[2], hB[2];
      #pragma unroll
      for(int e = 0; e < 2; e++){
        float gi = sigm (rr[4*e+0] + rr[16+4*e+0] + b1g[4*e+0]);
        float gf = sigm (rr[4*e+1] + rr[16+4*e+1] + b1g[4*e+1]);
        float gg = tanh_f(rr[4*e+2] + rr[16+4*e+2] + b1g[4*e+2]);
        float go = sigm (rr[4*e+3] + rr[16+4*e+3] + b1g[4*e+3]);
        c1[e] = gf*c1[e] + gi*gg;
        h1v[e] = go * tanh_f(c1[e]);

        float a0c = rr[8+4*e+0], a1c = rr[8+4*e+1], a2c = rr[8+4*e+2], a3c = rr[8+4*e+3];
        float giA = sigm (a0c + b0g[4*e+0]);
        float gfA = sigm (a1c + b0g[4*e+1]);
        float ggA = tanh_f(a2c + b0g[4*e+2]);
        float goA = sigm (a3c + b0g[4*e+3]);
        c0A[e] = gfA*c0[e] + giA*ggA; hA[e] = goA * tanh_f(c0A[e]);
        float giB = sigm (a0c + w0g[4*e+0] + b0g[4*e+0]);
        float gfB = sigm (a1c + w0g[4*e+1] + b0g[4*e+1]);
        float ggB = tanh_f(a2c + w0g[4*e+2] + b0g[4*e+2]);
        float goB = sigm (a3c + w0g[4*e+3] + b0g[4*e+3]);
        c0B[e] = gfB*c0[e] + giB*ggB; hB[e] = goB * tanh_f(c0B[e]);
      }
      if(lane == 0){
        unsigned long long* wb = ab + ((size_t)((tau + 1u) & 1u) << 10);
        st_slot(wb + 2*wg,     pack_rec(h1v[0], hA[0], hB[0], tau + 1u));
        st_slot(wb + 2*wg + 1, pack_rec(h1v[1], hA[1], hB[1], tau + 1u));
      }
    }

    // off critical path: logp/out + next RNG
    logp += sv * __logf(p) + (1.f - sv) * __logf(1.f - p);
    if(wg == 0 && lane == 0) out[t] = sv;
    {
      const uint32_t tn = (uint32_t)t + 1u;
      const uint32_t kk0 = jax_word(2u*tn), kk1 = jax_word(2u*tn + 1u);
      const uint32_t bits = tf2x32(kk0, kk1, 0u, 0u).x;
      u = __uint_as_float((bits >> 9) | 0x3f800000u) - 1.0f;
    }
  }

  if(wg == 0 && lane == 0) out[NSTEP] = logp;
}

extern "C" void kernel_launch(void* const* d_in, const int* in_sizes, int n_in,
                              void* d_out, int out_size, void* d_ws, size_t ws_size,
                              hipStream_t stream){
  unsigned long long* ws = (unsigned long long*)d_ws;
  unsigned long long* h0boot = ws;        // 512 slots (bootstrap)
  unsigned long long* ab     = ws + 512;  // 2 x 1024 parity record slots
  hipLaunchKernelGGL(lstm_persist, dim3(NWG), dim3(BLK), 0, stream,
    (const float*)d_in[0],  (const float*)d_in[1],  (const float*)d_in[2],
    (const float*)d_in[3],  (const float*)d_in[4],  (const float*)d_in[5],  (const float*)d_in[6],
    (const float*)d_in[7],  (const float*)d_in[8],  (const float*)d_in[9],  (const float*)d_in[10],
    (const float*)d_in[11], (const float*)d_in[12],
    (float*)d_out, h0boot, ab);
}

// Round 12
// 32768.488 us; speedup vs baseline: 1.9096x; 1.9096x over previous
//
#include <hip/hip_runtime.h>
#include <stdint.h>
#include <math.h>

// Persistent barrier-free 2-layer LSTM rollout, MI355X (gfx950).
// FINAL (= v10, best verified: 32.86ms). Session ledger (12 experiments):
//   structure: 2 broadcast rounds/step (h0 then h1), 512 WGs x 1 wave,
//   lazy sentinel+batch+pipelined poll, shadow Whh0/Whh1 rows + RNG.
//   Lambda (~1.75us/hop) proven intrinsic store->visibility latency:
//   insensitive to sampling rate (v10), lane count (v9), distribution
//   (v8), walk order (v6), publish mechanism (v11), ordering (v5/v7).
//   Hop-count reduction refuted 3x (v4/v7: +17%; v12: +90%, unstable).
//   Floor: 8192 x (2*1.75 + 0.5)us ~= 32.8ms. This kernel sits on it.
//
// 512 WGs x 64 thr (1 wave); wave w owns h-units {2w, 2w+1} of both layers.
// Critical chain/step: poll h0 -> 8 gate rows -> publish h1 ->
//                      poll h1 -> W2 row -> cell0 -> publish h0.
// Whh0/Whh1 rows + threefry RNG run post-publish (shadow time).

#define H     1024
#define NSTEP 8192
#define NWG   512
#define BLK   64
#define NROW  25   // 0-7 Wih1 (4 gates x 2 units), 8-15 Whh0, 16-23 Whh1, 24 W2

typedef _Float16 h2 __attribute__((ext_vector_type(2)));
typedef _Float16 h8 __attribute__((ext_vector_type(8)));

union U32H2 { uint32_t u; h2 v; };

__device__ __forceinline__ unsigned long long pack_vt(float v0, float v1, uint32_t tag){
  U32H2 p; p.v.x = (_Float16)v0; p.v.y = (_Float16)v1;
  return ((unsigned long long)tag << 32) | (unsigned long long)p.u;
}

// Exact JAX threefry2x32.
__device__ __forceinline__ uint2 tf2x32(uint32_t k0, uint32_t k1, uint32_t x0, uint32_t x1){
  uint32_t k2 = k0 ^ k1 ^ 0x1BD11BDAu;
  x0 += k0; x1 += k1;
#define TFR(r) { x0 += x1; x1 = (x1 << (r)) | (x1 >> (32 - (r))); x1 ^= x0; }
  TFR(13) TFR(15) TFR(26) TFR(6)
  x0 += k1; x1 += k2 + 1u;
  TFR(17) TFR(29) TFR(16) TFR(24)
  x0 += k2; x1 += k0 + 2u;
  TFR(13) TFR(15) TFR(26) TFR(6)
  x0 += k0; x1 += k1 + 3u;
  TFR(17) TFR(29) TFR(16) TFR(24)
  x0 += k1; x1 += k2 + 4u;
  TFR(13) TFR(15) TFR(26) TFR(6)
  x0 += k2; x1 += k0 + 5u;
#undef TFR
  uint2 r; r.x = x0; r.y = x1; return r;
}

// keys = threefry_split(key(42), 8192)
__device__ __forceinline__ uint32_t jax_word(uint32_t i){
  return (i < 8192u) ? tf2x32(0u, 42u, i, i + 8192u).x
                     : tf2x32(0u, 42u, i - 8192u, i).y;
}

__device__ __forceinline__ float wred64(float x){
  #pragma unroll
  for(int off = 32; off > 0; off >>= 1) x += __shfl_xor(x, off, 64);
  return x;
}

#if __has_builtin(__builtin_amdgcn_fdot2)
__device__ __forceinline__ float fdot2f(h2 a, h2 b, float c){ return __builtin_amdgcn_fdot2(a, b, c, false); }
#else
__device__ __forceinline__ float fdot2f(h2 a, h2 b, float c){
  return (float)a.x * (float)b.x + (float)a.y * (float)b.y + c;
}
#endif

__device__ __forceinline__ float sigm(float x){
  x = fminf(fmaxf(x, -30.f), 30.f);
  return 1.f / (1.f + __expf(-x));
}
__device__ __forceinline__ float tanh_f(float x){
  x = fminf(fmaxf(x, -15.f), 15.f);
  float e = __expf(2.f * x);
  return (e - 1.f) / (e + 1.f);
}

__device__ __forceinline__ unsigned long long ld_slot(const unsigned long long* p){
  return __hip_atomic_load((unsigned long long*)p, __ATOMIC_RELAXED, __HIP_MEMORY_SCOPE_AGENT);
}

// 2-deep pipelined spin on one slot: two staggered loads in flight,
// alternate-check -> sampling period ~RT/2 (serial dependent chain = RT).
__device__ __forceinline__ unsigned long long spin2(const unsigned long long* p,
                                                    uint32_t tag,
                                                    unsigned long long init){
  if((uint32_t)(init >> 32) == tag) return init;
  unsigned long long a = ld_slot(p);
  unsigned long long b = ld_slot(p);
  while(true){
    if((uint32_t)(a >> 32) == tag) return a;
    a = ld_slot(p);
    if((uint32_t)(b >> 32) == tag) return b;
    b = ld_slot(p);
  }
}

// Poll this lane's 8 slots (fragment pairs [4l,4l+4) and [256+4l,+4)).
// phase 0: batched initial snapshot
// phase 1: 2-deep pipelined sentinel spin on slot 0
// phase 2: one batched concurrent reload of the stale remainder (~1 RT)
// phase 3: 2-deep pipelined walk for stragglers
__device__ __forceinline__ void poll_h(const unsigned long long* __restrict__ buf,
                                       uint32_t tag, int lane, h2* hv){
  const unsigned long long* p0 = buf + (lane << 2);
  const unsigned long long* p1 = buf + 256 + (lane << 2);
  unsigned long long pv[8];
  #pragma unroll
  for(int k = 0; k < 4; k++) pv[k]     = ld_slot(p0 + k);
  #pragma unroll
  for(int k = 0; k < 4; k++) pv[4 + k] = ld_slot(p1 + k);

  // phase 1: pipelined sentinel
  pv[0] = spin2(p0, tag, pv[0]);

  // phase 2: batched refresh of whatever is still stale
  bool any = false;
  #pragma unroll
  for(int k = 1; k < 8; k++) any |= ((uint32_t)(pv[k] >> 32) != tag);
  if(any){
    #pragma unroll
    for(int k = 1; k < 8; k++){
      if((uint32_t)(pv[k] >> 32) != tag){
        const unsigned long long* p = (k < 4) ? (p0 + k) : (p1 + (k - 4));
        pv[k] = ld_slot(p);
      }
    }
    // phase 3: stragglers — pipelined per-slot spin
    #pragma unroll
    for(int k = 1; k < 8; k++){
      const unsigned long long* p = (k < 4) ? (p0 + k) : (p1 + (k - 4));
      pv[k] = spin2(p, tag, pv[k]);
    }
  }

  #pragma unroll
  for(int k = 0; k < 8; k++){
    U32H2 u; u.u = (uint32_t)pv[k];
    hv[k] = u.v;
  }
}

// Row dot partial: lane l covers h2 [4l,4l+4) and [256+4l,+4): two b128
// LDS reads, lane stride 16B -> conflict-free.
__device__ __forceinline__ float row_part(const h2* __restrict__ wrow, int lane, const h2* hv){
  h8 wl = *(const h8*)(wrow + (lane << 2));
  h8 wh = *(const h8*)(wrow + 256 + (lane << 2));
  float a0 = 0.f, a1 = 0.f;
  h2 w;
  w = __builtin_shufflevector(wl, wl, 0, 1); a0 = fdot2f(w, hv[0], a0);
  w = __builtin_shufflevector(wl, wl, 2, 3); a1 = fdot2f(w, hv[1], a1);
  w = __builtin_shufflevector(wl, wl, 4, 5); a0 = fdot2f(w, hv[2], a0);
  w = __builtin_shufflevector(wl, wl, 6, 7); a1 = fdot2f(w, hv[3], a1);
  w = __builtin_shufflevector(wh, wh, 0, 1); a0 = fdot2f(w, hv[4], a0);
  w = __builtin_shufflevector(wh, wh, 2, 3); a1 = fdot2f(w, hv[5], a1);
  w = __builtin_shufflevector(wh, wh, 4, 5); a0 = fdot2f(w, hv[6], a0);
  w = __builtin_shufflevector(wh, wh, 6, 7); a1 = fdot2f(w, hv[7], a1);
  return a0 + a1;
}

__global__ void __launch_bounds__(BLK)
lstm_persist(const float* __restrict__ ctx,  const float* __restrict__ W1p,  const float* __restrict__ b1p,
             const float* __restrict__ Wih0, const float* __restrict__ Whh0,
             const float* __restrict__ bih0, const float* __restrict__ bhh0,
             const float* __restrict__ Wih1, const float* __restrict__ Whh1,
             const float* __restrict__ bih1, const float* __restrict__ bhh1,
             const float* __restrict__ W2p,  const float* __restrict__ b2p,
             float* __restrict__ out,
             unsigned long long* __restrict__ h0buf,
             unsigned long long* __restrict__ h1buf)
{
  __shared__ h2 w[NROW][H/2];   // 51.2 KB (<64KB/block cap); 2 WGs/CU

  const int lane = threadIdx.x;   // single wave per WG
  const int wg   = blockIdx.x;
  const int j0   = wg << 1;       // this wave's two h-units: j0, j0+1

  // ---- one-time: stage 25 rows as f16 (coalesced float4 reads)
  #pragma unroll 1
  for(int r = 0; r < NROW; r++){
    const float* rowp;
    if(r < 8)      { int g = r & 3,        j = j0 + (r >> 2);        rowp = Wih1 + (size_t)(g*H + j)*H; }
    else if(r < 16){ int rr = r - 8;  int g = rr & 3, j = j0 + (rr >> 2); rowp = Whh0 + (size_t)(g*H + j)*H; }
    else if(r < 24){ int rr = r - 16; int g = rr & 3, j = j0 + (rr >> 2); rowp = Whh1 + (size_t)(g*H + j)*H; }
    else           rowp = W2p;
    const float4* s4 = (const float4*)rowp;
    #pragma unroll
    for(int it = 0; it < 4; it++){
      float4 f = s4[lane + (it << 6)];
      h2 pa; pa.x = (_Float16)f.x; pa.y = (_Float16)f.y;
      h2 pb; pb.x = (_Float16)f.z; pb.y = (_Float16)f.w;
      const int ci = (lane + (it << 6)) << 1;
      w[r][ci] = pa; w[r][ci + 1] = pb;
    }
  }
  __syncthreads();

  // per-wave scalars for both units (uniform across lanes)
  float b0g[8], b1g[8], w0g[8];
  #pragma unroll
  for(int e = 0; e < 2; e++){
    const int j = j0 + e;
    #pragma unroll
    for(int g = 0; g < 4; g++){
      b0g[4*e + g] = bih0[g*H + j] + bhh0[g*H + j];
      b1g[4*e + g] = bih1[g*H + j] + bhh1[g*H + j];
      w0g[4*e + g] = Wih0[g*H + j];
    }
  }
  const float b2v = b2p[0];

  // x0 = W1 @ context + b1
  float xacc = 0.f;
  for(int c = lane; c < 512; c += 64) xacc += W1p[c] * ctx[c];
  const float x0 = wred64(xacc) + b1p[0];

  float c0[2], c1[2] = {0.f, 0.f}, logp = 0.f;
  float a0[8];
  float a1[8] = {0.f,0.f,0.f,0.f,0.f,0.f,0.f,0.f};

  // h0(0) from x0 for both units
  {
    float h0v[2];
    #pragma unroll
    for(int e = 0; e < 2; e++){
      float gi = sigm (w0g[4*e+0]*x0 + b0g[4*e+0]);
      float gg = tanh_f(w0g[4*e+2]*x0 + b0g[4*e+2]);
      float go = sigm (w0g[4*e+3]*x0 + b0g[4*e+3]);
      c0[e] = gi * gg;
      h0v[e] = go * tanh_f(c0[e]);
    }
    if(lane == 0)
      __hip_atomic_store(&h0buf[wg], pack_vt(h0v[0], h0v[1], 1u),
                         __ATOMIC_RELAXED, __HIP_MEMORY_SCOPE_AGENT);
  }

  h2 hv[8];
  float u = 0.f;

  #pragma unroll 1
  for(int t = 0; t < NSTEP; t++){
    const uint32_t tt = (uint32_t)t;

    // ================= P1: consume h0(t) =================
    poll_h(h0buf, tt + 1u, lane, hv);

    // critical: 8 layer-1 gate rows (Wih1, both units)
    float s1[8];
    #pragma unroll
    for(int r = 0; r < 8; r++) s1[r] = row_part(&w[r][0], lane, hv);
    #pragma unroll
    for(int off = 32; off > 0; off >>= 1){
      #pragma unroll
      for(int r = 0; r < 8; r++) s1[r] += __shfl_xor(s1[r], off, 64);
    }
    {
      float h1v[2];
      #pragma unroll
      for(int e = 0; e < 2; e++){
        float gi = sigm (s1[4*e+0] + a1[4*e+0] + b1g[4*e+0]);
        float gf = sigm (s1[4*e+1] + a1[4*e+1] + b1g[4*e+1]);
        float gg = tanh_f(s1[4*e+2] + a1[4*e+2] + b1g[4*e+2]);
        float go = sigm (s1[4*e+3] + a1[4*e+3] + b1g[4*e+3]);
        c1[e] = gf*c1[e] + gi*gg;
        h1v[e] = go * tanh_f(c1[e]);
      }
      if(lane == 0)
        __hip_atomic_store(&h1buf[wg], pack_vt(h1v[0], h1v[1], tt + 1u),
                           __ATOMIC_RELAXED, __HIP_MEMORY_SCOPE_AGENT);
    }

    // shadow: RNG + 8 Whh0 rows (a0 for P2's cell0)
    {
      const uint32_t kk0 = jax_word(2u*tt), kk1 = jax_word(2u*tt + 1u);
      const uint32_t bits = tf2x32(kk0, kk1, 0u, 0u).x;
      u = __uint_as_float((bits >> 9) | 0x3f800000u) - 1.0f;
    }
    float sa[8];
    #pragma unroll
    for(int r = 0; r < 8; r++) sa[r] = row_part(&w[8 + r][0], lane, hv);
    #pragma unroll
    for(int off = 32; off > 0; off >>= 1){
      #pragma unroll
      for(int r = 0; r < 8; r++) sa[r] += __shfl_xor(sa[r], off, 64);
    }
    #pragma unroll
    for(int r = 0; r < 8; r++) a0[r] = sa[r];

    // ================= P2: consume h1(t) =================
    poll_h(h1buf, tt + 1u, lane, hv);

    // critical: W2 row -> p,s -> cell0 -> publish h0(t+1)
    float z = row_part(&w[24][0], lane, hv);
    z = wred64(z) + b2v;
    const float p = sigm(z);
    const float s = (u < p) ? 1.f : 0.f;
    {
      float h0v[2];
      #pragma unroll
      for(int e = 0; e < 2; e++){
        float gi = sigm (a0[4*e+0] + w0g[4*e+0]*s + b0g[4*e+0]);
        float gf = sigm (a0[4*e+1] + w0g[4*e+1]*s + b0g[4*e+1]);
        float gg = tanh_f(a0[4*e+2] + w0g[4*e+2]*s + b0g[4*e+2]);
        float go = sigm (a0[4*e+3] + w0g[4*e+3]*s + b0g[4*e+3]);
        c0[e] = gf*c0[e] + gi*gg;
        h0v[e] = go * tanh_f(c0[e]);
      }
      if(lane == 0)
        __hip_atomic_store(&h0buf[wg], pack_vt(h0v[0], h0v[1], tt + 2u),
                           __ATOMIC_RELAXED, __HIP_MEMORY_SCOPE_AGENT);
    }

    // off critical path: logp/out after the publish
    logp += s * __logf(p) + (1.f - s) * __logf(1.f - p);
    if(wg == 0 && lane == 0) out[t] = s;

    // shadow: 8 Whh1 rows (a1 for next step's P1)
    float sb[8];
    #pragma unroll
    for(int r = 0; r < 8; r++) sb[r] = row_part(&w[16 + r][0], lane, hv);
    #pragma unroll
    for(int off = 32; off > 0; off >>= 1){
      #pragma unroll
      for(int r = 0; r < 8; r++) sb[r] += __shfl_xor(sb[r], off, 64);
    }
    #pragma unroll
    for(int r = 0; r < 8; r++) a1[r] = sb[r];
  }

  if(wg == 0 && lane == 0) out[NSTEP] = logp;
}

extern "C" void kernel_launch(void* const* d_in, const int* in_sizes, int n_in,
                              void* d_out, int out_size, void* d_ws, size_t ws_size,
                              hipStream_t stream){
  unsigned long long* h0buf = (unsigned long long*)d_ws;   // 512 slots
  unsigned long long* h1buf = h0buf + 512;                 // 512 slots
  hipLaunchKernelGGL(lstm_persist, dim3(NWG), dim3(BLK), 0, stream,
    (const float*)d_in[0],  (const float*)d_in[1],  (const float*)d_in[2],
    (const float*)d_in[3],  (const float*)d_in[4],  (const float*)d_in[5],  (const float*)d_in[6],
    (const float*)d_in[7],  (const float*)d_in[8],  (const float*)d_in[9],  (const float*)d_in[10],
    (const float*)d_in[11], (const float*)d_in[12],
    (float*)d_out, h0buf, h1buf);
}